// Round 9
// baseline (108.501 us; speedup 1.0000x reference)
//
#include <hip/hip_runtime.h>
#include <hip/hip_bf16.h>
#include <cstdint>

// B=8, S=1024, D=512, H=8, DK=64. All-bf16 MFMA pipeline.
// attn v7: 8 waves = 4 q-waves x 2 k-halves (in-block k-split, additive merge).
// R9 = R8 minus the two wounds: launch_bounds(512,2) (R8's (512,4) forced
// 64-VGPR budget -> 17MB scratch spill traffic) and stride-66 merge layout
// (R8's stride-64 was a 16-way bank conflict, 1.37M hits).

typedef __attribute__((ext_vector_type(8))) short short8;
typedef __attribute__((ext_vector_type(4))) float f32x4;

__device__ __forceinline__ ushort f2bf(float x) {
    union { __hip_bfloat16 h; ushort u; } v;
    v.h = __float2bfloat16(x);
    return v.u;
}
__device__ __forceinline__ float bf2f(ushort u) {
    union { uint u; float f; } v; v.u = ((uint)u) << 16; return v.f;
}
__device__ __forceinline__ uint cvtpk(float lo, float hi) {
    uint r;
    asm("v_cvt_pk_bf16_f32 %0, %1, %2" : "=v"(r) : "v"(lo), "v"(hi));
    return r;
}
__device__ __forceinline__ f32x4 mfma16(short8 a, short8 b, f32x4 c) {
    return __builtin_amdgcn_mfma_f32_16x16x32_bf16(a, b, c, 0, 0, 0);
}
// async global->LDS, 16B per lane. LDS dest = wave-uniform base + lane*16.
__device__ __forceinline__ void gl16(const void* g, const void* l) {
    __builtin_amdgcn_global_load_lds(
        (const __attribute__((address_space(1))) uint32_t*)(uintptr_t)g,
        (__attribute__((address_space(3))) uint32_t*)(uint32_t)(uintptr_t)l,
        16, 0, 0);
}

// ---------------------------------------------------------------------------
// prep: gm fuse + fp32->bf16 conversions (unchanged, known-good)
// ---------------------------------------------------------------------------
__global__ __launch_bounds__(256)
void prep(const float* __restrict__ q, const float* __restrict__ k,
          const float* __restrict__ v,
          const float* __restrict__ wq, const float* __restrict__ wk,
          const float* __restrict__ wv, const float* __restrict__ wh,
          const int* __restrict__ mask, const float* __restrict__ gp,
          ushort* __restrict__ qb, ushort* __restrict__ kb,
          ushort* __restrict__ vb,
          ushort* __restrict__ wqb, ushort* __restrict__ wkb,
          ushort* __restrict__ wvb, ushort* __restrict__ whb,
          ushort* __restrict__ gmb)
{
    const int bid = blockIdx.x, tid = threadIdx.x;
    if (bid < 8192) {
        size_t i = ((size_t)bid * 256 + tid) * 4;
        int4 m = *(const int4*)(mask + i);
        float4 gg = *(const float4*)(gp + i);
        int kk = (int)(i & 1023), qq = (int)((i >> 10) & 1023);
        uint u01 = cvtpk(gg.x, gg.y), u23 = cvtpk(gg.z, gg.w);
        ushort4 o;
        o.x = (m.x != 0 || qq == kk + 0) ? (ushort)(u01 & 0xffff) : (ushort)0xBF80;
        o.y = (m.y != 0 || qq == kk + 1) ? (ushort)(u01 >> 16)    : (ushort)0xBF80;
        o.z = (m.z != 0 || qq == kk + 2) ? (ushort)(u23 & 0xffff) : (ushort)0xBF80;
        o.w = (m.w != 0 || qq == kk + 3) ? (ushort)(u23 >> 16)    : (ushort)0xBF80;
        *(ushort4*)(gmb + i) = o;
    } else if (bid < 20480) {
        size_t id = ((size_t)(bid - 8192) * 256 + tid) * 4;
        int t = (int)(id >> 22);
        size_t off = id & 4194303;
        const float* s = (t == 0) ? q : (t == 1) ? k : v;
        ushort* d = (t == 0) ? qb : (t == 1) ? kb : vb;
        float4 x = *(const float4*)(s + off);
        uint2 o; o.x = cvtpk(x.x, x.y); o.y = cvtpk(x.z, x.w);
        *(uint2*)(d + off) = o;
    } else {
        size_t id = ((size_t)(bid - 20480) * 256 + tid) * 4;
        int t = (int)(id >> 18);
        size_t off = id & 262143;
        const float* s = (t == 0) ? wq : (t == 1) ? wk : (t == 2) ? wv : wh;
        ushort* d = (t == 0) ? wqb : (t == 1) ? wkb : (t == 2) ? wvb : whb;
        float4 x = *(const float4*)(s + off);
        uint2 o; o.x = cvtpk(x.x, x.y); o.y = cvtpk(x.z, x.w);
        *(uint2*)(d + off) = o;
    }
}

// ---------------------------------------------------------------------------
// QKV GEMM (unchanged, known-good)
// ---------------------------------------------------------------------------
__global__ __launch_bounds__(256, 2)
void gemm3(const ushort* __restrict__ qb, const ushort* __restrict__ kb,
           const ushort* __restrict__ vb,
           const ushort* __restrict__ Wqb, const ushort* __restrict__ Wkb,
           const ushort* __restrict__ Wvb,
           ushort* __restrict__ q_ws, ushort* __restrict__ k_ws,
           ushort* __restrict__ vT)
{
    __shared__ __attribute__((aligned(16))) ushort As[8192];
    __shared__ __attribute__((aligned(16))) ushort Bs[8192];

    const int z = blockIdx.z;
    const ushort* A = (z == 0) ? qb : (z == 1) ? kb : Wvb;
    const ushort* B = (z == 0) ? Wqb : (z == 1) ? Wkb : vb;
    const int mt = (z == 2) ? blockIdx.y : blockIdx.x;
    const int nt = (z == 2) ? blockIdx.x : blockIdx.y;
    const int m0 = mt * 128, n0 = nt * 128;
    const int tid = threadIdx.x, lane = tid & 63, wave = tid >> 6;
    const int l15 = lane & 15, g = lane >> 4;
    const int wm = wave >> 1, wn = wave & 1;

    const int cb = (lane & 7) << 4;
    int soff[4];
    #pragma unroll
    for (int it = 0; it < 4; ++it) {
        int r = (it * 4 + wave) * 8 + (lane >> 3);
        soff[it] = r * 1024 + (cb ^ ((r & 7) << 4));
    }
    const char* Ab = (const char*)A + (size_t)m0 * 1024;
    const char* Bb = (const char*)B + (size_t)n0 * 1024;

    const int sw = (l15 & 7) << 4;
    const int c0 = (g * 16) ^ sw;
    const int c1 = (64 + g * 16) ^ sw;

    f32x4 acc[4][4];
    #pragma unroll
    for (int i = 0; i < 4; ++i)
        #pragma unroll
        for (int j = 0; j < 4; ++j) acc[i][j] = (f32x4){0.f, 0.f, 0.f, 0.f};

    for (int ks = 0; ks < 8; ++ks) {
        const int kof = ks * 128;
        #pragma unroll
        for (int it = 0; it < 4; ++it) {
            gl16(Ab + soff[it] + kof, (const char*)As + (it * 4 + wave) * 1024);
            gl16(Bb + soff[it] + kof, (const char*)Bs + (it * 4 + wave) * 1024);
        }
        __syncthreads();
        #pragma unroll
        for (int kk = 0; kk < 2; ++kk) {
            const int cc = kk ? c1 : c0;
            short8 af[4], bf[4];
            #pragma unroll
            for (int i = 0; i < 4; ++i)
                af[i] = *(const short8*)((const char*)As + (wm * 64 + i * 16 + l15) * 128 + cc);
            #pragma unroll
            for (int j = 0; j < 4; ++j)
                bf[j] = *(const short8*)((const char*)Bs + (wn * 64 + j * 16 + l15) * 128 + cc);
            #pragma unroll
            for (int i = 0; i < 4; ++i)
                #pragma unroll
                for (int j = 0; j < 4; ++j)
                    acc[i][j] = mfma16(af[i], bf[j], acc[i][j]);
        }
        __syncthreads();
    }

    #pragma unroll
    for (int i = 0; i < 4; ++i) {
        #pragma unroll
        for (int j = 0; j < 4; ++j) {
            #pragma unroll
            for (int r = 0; r < 4; ++r) {
                int mm = m0 + wm * 64 + i * 16 + g * 4 + r;
                int nn = n0 + wn * 64 + j * 16 + l15;
                float val = acc[i][j][r];
                if (z == 0) {
                    val *= 0.18033688f;   // 1/sqrt(64) * log2(e) folded into Q
                    int b = mm >> 10, s = mm & 1023, h = nn >> 6, dk = nn & 63;
                    q_ws[((((size_t)(b * 8 + h)) << 10) + s) * 64 + dk] = f2bf(val);
                } else if (z == 1) {
                    int b = mm >> 10, s = mm & 1023, h = nn >> 6, dk = nn & 63;
                    k_ws[((((size_t)(b * 8 + h)) << 10) + s) * 64 + dk] = f2bf(val);
                } else {
                    int h = mm >> 6, d = mm & 63, b = nn >> 10, s = nn & 1023;
                    vT[(((size_t)(b * 8 + h) * 64 + d) << 10) + s] = f2bf(val);
                }
            }
        }
    }
}

// ---------------------------------------------------------------------------
// Out projection (unchanged, known-good)
// ---------------------------------------------------------------------------
__global__ __launch_bounds__(256, 2)
void gemm_o(const ushort* __restrict__ Xh, const ushort* __restrict__ Whb,
            const float* __restrict__ bias, float* __restrict__ out)
{
    __shared__ __attribute__((aligned(16))) ushort As[8192];
    __shared__ __attribute__((aligned(16))) ushort Bs[8192];

    const int m0 = blockIdx.x * 128, n0 = blockIdx.y * 128;
    const int tid = threadIdx.x, lane = tid & 63, wave = tid >> 6;
    const int l15 = lane & 15, g = lane >> 4;
    const int wm = wave >> 1, wn = wave & 1;
    const int bb = m0 >> 10, s0 = m0 & 1023;

    const int cb = (lane & 7) << 4;
    int aoff[4], boff[4];
    #pragma unroll
    for (int it = 0; it < 4; ++it) {
        int r = (it * 4 + wave) * 8 + (lane >> 3);
        int swz = cb ^ ((r & 7) << 4);
        aoff[it] = ((bb * 8) * 1024 + s0 + r) * 128 + swz;  // +ks*131072
        boff[it] = (n0 + r) * 1024 + swz;                   // +ks*128
    }
    const int sw = (l15 & 7) << 4;
    const int c0 = (g * 16) ^ sw;
    const int c1 = (64 + g * 16) ^ sw;

    f32x4 acc[4][4];
    #pragma unroll
    for (int i = 0; i < 4; ++i)
        #pragma unroll
        for (int j = 0; j < 4; ++j) acc[i][j] = (f32x4){0.f, 0.f, 0.f, 0.f};

    for (int ks = 0; ks < 8; ++ks) {
        #pragma unroll
        for (int it = 0; it < 4; ++it) {
            gl16((const char*)Xh + aoff[it] + ks * 131072,
                 (const char*)As + (it * 4 + wave) * 1024);
            gl16((const char*)Whb + boff[it] + ks * 128,
                 (const char*)Bs + (it * 4 + wave) * 1024);
        }
        __syncthreads();
        #pragma unroll
        for (int kk = 0; kk < 2; ++kk) {
            const int cc = kk ? c1 : c0;
            short8 af[4], bf[4];
            #pragma unroll
            for (int i = 0; i < 4; ++i)
                af[i] = *(const short8*)((const char*)As + (wm * 64 + i * 16 + l15) * 128 + cc);
            #pragma unroll
            for (int j = 0; j < 4; ++j)
                bf[j] = *(const short8*)((const char*)Bs + (wn * 64 + j * 16 + l15) * 128 + cc);
            #pragma unroll
            for (int i = 0; i < 4; ++i)
                #pragma unroll
                for (int j = 0; j < 4; ++j)
                    acc[i][j] = mfma16(af[i], bf[j], acc[i][j]);
        }
        __syncthreads();
    }

    float bv[4];
    #pragma unroll
    for (int j = 0; j < 4; ++j) bv[j] = bias[n0 + wn * 64 + j * 16 + l15];

    #pragma unroll
    for (int i = 0; i < 4; ++i)
        #pragma unroll
        for (int j = 0; j < 4; ++j)
            #pragma unroll
            for (int r = 0; r < 4; ++r) {
                int mm = m0 + wm * 64 + i * 16 + g * 4 + r;
                int nn = n0 + wn * 64 + j * 16 + l15;
                out[(size_t)mm * 512 + nn] = acc[i][j][r] + bv[j];
            }
}

// ---------------------------------------------------------------------------
// attn v7: 8 waves = 4 q-waves (32q each) x 2 k-halves (512k each).
// Grid 512 (w = qt*64 + bh -> XCD = bh%8 = h). Each half: 8 tiles of 64 keys,
// double-buffered 16KB LDS stages (exactly-once gl16 chunk map), sigma
// row-permuted K + XOR swizzle on SOURCE+READ, linear gm reg prefetch.
// No online max (additive softmax) -> halves merge by plain sum in LDS
// (stride-66 padded, conflict-free). launch_bounds(512,2): 128-VGPR budget.
// ---------------------------------------------------------------------------
__device__ __forceinline__ void softmax16(const short8 gc0, const short8 gc1,
                                          const f32x4 (&s4)[4], float& lsum,
                                          uint4& u0, uint4& u1)
{
    float p[16], gv[16];
    #pragma unroll
    for (int c = 0; c < 2; ++c) {
        const short8 gc = c ? gc1 : gc0;
        #pragma unroll
        for (int j = 0; j < 8; ++j) {
            const int jj = c * 8 + j;
            const int t4 = 2 * c + (j >> 2), r = j & 3;
            float gvv = bf2f((ushort)gc[j]);
            gv[jj] = gvv;
            p[jj] = exp2f((gvv >= 0.f) ? s4[t4][r] : -1.0e9f);
        }
    }
    lsum += (((p[0] + p[1]) + (p[2] + p[3])) + ((p[4] + p[5]) + (p[6] + p[7])))
          + (((p[8] + p[9]) + (p[10] + p[11])) + ((p[12] + p[13]) + (p[14] + p[15])));
    u0.x = cvtpk(p[0] * gv[0],  p[1] * gv[1]);
    u0.y = cvtpk(p[2] * gv[2],  p[3] * gv[3]);
    u0.z = cvtpk(p[4] * gv[4],  p[5] * gv[5]);
    u0.w = cvtpk(p[6] * gv[6],  p[7] * gv[7]);
    u1.x = cvtpk(p[8] * gv[8],  p[9] * gv[9]);
    u1.y = cvtpk(p[10] * gv[10], p[11] * gv[11]);
    u1.z = cvtpk(p[12] * gv[12], p[13] * gv[13]);
    u1.w = cvtpk(p[14] * gv[14], p[15] * gv[15]);
}

__global__ __launch_bounds__(512, 2)
void attn(const ushort* __restrict__ Qh, const ushort* __restrict__ Kh,
          const ushort* __restrict__ Vt, const ushort* __restrict__ gm,
          ushort* __restrict__ xo)
{
    __shared__ __attribute__((aligned(16))) char lds[65536];
    // [buf 0/1: 32KB][half ks: 16KB = K 8KB + V 8KB]; merge reuses as f32.

    const int w = blockIdx.x;            // 0..511
    const int bh = w & 63, qt = w >> 6;  // qt 0..7
    const int tid = threadIdx.x, wave = tid >> 6, lane = tid & 63;
    const int l15 = lane & 15, g = lane >> 4;
    const int ks = wave >> 2, wq = wave & 3;
    const int q0 = qt * 128 + wq * 32;
    const int b = bh >> 3;

    const char* Kpb = (const char*)(Kh + (size_t)bh * 65536) + ks * 65536;
    const char* Vpb = (const char*)(Vt + (size_t)bh * 65536) + ks * 1024;
    const ushort* QpA = Qh + ((size_t)bh * 1024 + q0 + l15) * 64;
    const ushort* QpB = QpA + 1024;            // +16 rows
    const ushort* gma  = gm + ((size_t)b * 1024 + q0 + l15) * 1024 + ks * 512 + g * 8;
    const ushort* gmb2 = gma + 16384;          // +16 q rows

    const short8 qa0 = *(const short8*)(QpA + g * 8);
    const short8 qa1 = *(const short8*)(QpA + 32 + g * 8);
    const short8 qb0 = *(const short8*)(QpB + g * 8);
    const short8 qb1 = *(const short8*)(QpB + 32 + g * 8);

    // exactly-once staging map: half's 4 waves stage its 16KB (16 chunks of
    // 1KB). wq 0-1 -> K chunks (rows 0..63, sigma-permuted source);
    // wq 2-3 -> V chunks (rows 0..63 identity).
    const int cbs = ((lane & 7) << 4) ^ ((lane >> 3) << 4);
    const char* sbase;
    int soff[4], doff[4], sstep;
    if (wq < 2) {
        sstep = 8192; sbase = Kpb;
        #pragma unroll
        for (int i = 0; i < 4; ++i) {
            int r = (wq * 4 + i) * 8 + (lane >> 3);
            int gk = (r & 3) + 4 * ((r >> 4) & 1) + 8 * ((r >> 2) & 3) + 32 * (r >> 5);
            soff[i] = gk * 128 + cbs;
            doff[i] = ks * 16384 + (wq * 4 + i) * 1024 + lane * 16;
        }
    } else {
        sstep = 128; sbase = Vpb;
        #pragma unroll
        for (int i = 0; i < 4; ++i) {
            int rv = ((wq - 2) * 4 + i) * 8 + (lane >> 3);
            soff[i] = rv * 2048 + cbs;
            doff[i] = ks * 16384 + 8192 + ((wq - 2) * 4 + i) * 1024 + lane * 16;
        }
    }

    const int sw = (l15 & 7) << 4;
    const int c0 = (g * 16) ^ sw;
    const int c1 = (64 + g * 16) ^ sw;

    f32x4 otA[4], otB[4];
    #pragma unroll
    for (int t = 0; t < 4; ++t) {
        otA[t] = (f32x4){0.f, 0.f, 0.f, 0.f};
        otB[t] = (f32x4){0.f, 0.f, 0.f, 0.f};
    }
    float lsA = 0.f, lsB = 0.f;

    // prologue: tile 0 -> buf 0; gm tile 0 -> regs
    #pragma unroll
    for (int i = 0; i < 4; ++i) gl16(sbase + soff[i], lds + doff[i]);
    short8 gcA0 = *(const short8*)(gma);
    short8 gcA1 = *(const short8*)(gma + 32);
    short8 gcB0 = *(const short8*)(gmb2);
    short8 gcB1 = *(const short8*)(gmb2 + 32);
    __syncthreads();

    for (int t = 0; t < 8; ++t) {
        const int cur = t & 1;
        short8 gnA0, gnA1, gnB0, gnB1;
        if (t < 7) {
            #pragma unroll
            for (int i = 0; i < 4; ++i)
                gl16(sbase + (t + 1) * sstep + soff[i],
                     lds + (cur ^ 1) * 32768 + doff[i]);
            gnA0 = *(const short8*)(gma + (t + 1) * 64);
            gnA1 = *(const short8*)(gma + (t + 1) * 64 + 32);
            gnB0 = *(const short8*)(gmb2 + (t + 1) * 64);
            gnB1 = *(const short8*)(gmb2 + (t + 1) * 64 + 32);
        }
        const char* kbuf = lds + cur * 32768 + ks * 16384;
        const char* vbuf = kbuf + 8192;

        // QK^T (swapped) for both Q-frags; K regs shared.
        f32x4 sA[4], sB[4];
        #pragma unroll
        for (int t4 = 0; t4 < 4; ++t4) {
            const char* ka = kbuf + (t4 * 16 + l15) * 128;
            short8 k0f = *(const short8*)(ka + c0);
            short8 k1f = *(const short8*)(ka + c1);
            f32x4 za = (f32x4){0.f, 0.f, 0.f, 0.f};
            za = mfma16(k0f, qa0, za);
            za = mfma16(k1f, qa1, za);
            sA[t4] = za;
            f32x4 zb = (f32x4){0.f, 0.f, 0.f, 0.f};
            zb = mfma16(k0f, qb0, zb);
            zb = mfma16(k1f, qb1, zb);
            sB[t4] = zb;
        }

        union { uint4 u; short8 s; } paA0, paA1, paB0, paB1;
        softmax16(gcA0, gcA1, sA, lsA, paA0.u, paA1.u);
        softmax16(gcB0, gcB1, sB, lsB, paB0.u, paB1.u);

        #pragma unroll
        for (int td = 0; td < 4; ++td) {
            const char* va = vbuf + (td * 16 + l15) * 128;
            short8 v0 = *(const short8*)(va + c0);
            short8 v1 = *(const short8*)(va + c1);
            otA[td] = mfma16(v0, paA0.s, otA[td]);
            otA[td] = mfma16(v1, paA1.s, otA[td]);
            otB[td] = mfma16(v0, paB0.s, otB[td]);
            otB[td] = mfma16(v1, paB1.s, otB[td]);
        }
        __syncthreads();
        if (t < 7) { gcA0 = gnA0; gcA1 = gnA1; gcB0 = gnB0; gcB1 = gnB1; }
    }

    // full per-q lsum within this half
    lsA += __shfl_xor(lsA, 16, 64);
    lsA += __shfl_xor(lsA, 32, 64);
    lsB += __shfl_xor(lsB, 16, 64);
    lsB += __shfl_xor(lsB, 32, 64);

    // additive merge of the two k-halves (LDS reused post-barrier).
    // stride 66 floats: bank = (l15*66 + td*16 + g*4)/1 %32 -> <=2-way (free).
    float* mO = (float*)lds;                    // [4 wq][32 q][66 pad]
    float* mL = (float*)(lds + 36864);          // [4 wq][32 q]
    if (ks == 1) {
        float* dA = mO + wq * 2112 + l15 * 66;
        float* dB = mO + wq * 2112 + (l15 + 16) * 66;
        #pragma unroll
        for (int td = 0; td < 4; ++td) {
            *(f32x4*)(dA + td * 16 + g * 4) = otA[td];
            *(f32x4*)(dB + td * 16 + g * 4) = otB[td];
        }
        if (g == 0) {
            mL[wq * 32 + l15] = lsA;
            mL[wq * 32 + 16 + l15] = lsB;
        }
    }
    __syncthreads();
    if (ks == 0) {
        const float invA = 1.0f / (lsA + mL[wq * 32 + l15]);
        const float invB = 1.0f / (lsB + mL[wq * 32 + 16 + l15]);
        const float* dA = mO + wq * 2112 + l15 * 66;
        const float* dB = mO + wq * 2112 + (l15 + 16) * 66;
        ushort* xpA = xo + ((size_t)bh * 1024 + q0 + l15) * 64;
        ushort* xpB = xpA + 1024;
        #pragma unroll
        for (int td = 0; td < 4; ++td) {
            f32x4 a2 = *(const f32x4*)(dA + td * 16 + g * 4);
            f32x4 b2 = *(const f32x4*)(dB + td * 16 + g * 4);
            uint2 oa, ob;
            oa.x = cvtpk((otA[td][0] + a2[0]) * invA, (otA[td][1] + a2[1]) * invA);
            oa.y = cvtpk((otA[td][2] + a2[2]) * invA, (otA[td][3] + a2[3]) * invA);
            ob.x = cvtpk((otB[td][0] + b2[0]) * invB, (otB[td][1] + b2[1]) * invB);
            ob.y = cvtpk((otB[td][2] + b2[2]) * invB, (otB[td][3] + b2[3]) * invB);
            *(uint2*)(xpA + td * 16 + g * 4) = oa;
            *(uint2*)(xpB + td * 16 + g * 4) = ob;
        }
    }
}

// ---------------------------------------------------------------------------
extern "C" void kernel_launch(void* const* d_in, const int* in_sizes, int n_in,
                              void* d_out, int out_size, void* d_ws, size_t ws_size,
                              hipStream_t stream)
{
    const float* query = (const float*)d_in[0];
    const float* key   = (const float*)d_in[1];
    const float* value = (const float*)d_in[2];
    const float* gprob = (const float*)d_in[3];
    const float* Wq    = (const float*)d_in[4];
    const float* Wk    = (const float*)d_in[5];
    const float* Wv    = (const float*)d_in[6];
    const float* Wh    = (const float*)d_in[7];
    const float* bh    = (const float*)d_in[8];
    const int*   mask  = (const int*)d_in[9];
    float* out = (float*)d_out;

    ushort* ws = (ushort*)d_ws;
    const size_t HS = (size_t)64 * 65536;   // 4,194,304
    ushort* q_ws = ws;
    ushort* k_ws = ws + HS;
    ushort* vT   = ws + 2 * HS;
    ushort* gmb  = ws + 3 * HS;             // 2*HS elems
    ushort* qb   = ws + 5 * HS;
    ushort* kb   = ws + 6 * HS;
    ushort* vb   = ws + 7 * HS;
    ushort* wqb  = ws + 8 * HS;
    ushort* wkb  = wqb + 262144;
    ushort* wvb  = wkb + 262144;
    ushort* whb  = wvb + 262144;
    ushort* x_ws = qb;                      // alias: qb dead after gemm3

    prep<<<21504, 256, 0, stream>>>(query, key, value, Wq, Wk, Wv, Wh,
                                    mask, gprob, qb, kb, vb,
                                    wqb, wkb, wvb, whb, gmb);
    gemm3<<<dim3(64, 4, 3), 256, 0, stream>>>(qb, kb, vb, wqb, wkb, wvb,
                                              q_ws, k_ws, vT);
    attn<<<512, 512, 0, stream>>>(q_ws, k_ws, vT, gmb, x_ws);
    gemm_o<<<dim3(64, 4), 256, 0, stream>>>(x_ws, whb, bh, out);
}

// Round 10
// 105.421 us; speedup vs baseline: 1.0292x; 1.0292x over previous
//
#include <hip/hip_runtime.h>
#include <hip/hip_bf16.h>
#include <cstdint>

// B=8, S=1024, D=512, H=8, DK=64. All-bf16 MFMA pipeline.
// R10: prep = qkv/W conversion only; gm production co-scheduled with the QKV
// GEMMs in one launch (fused_g) so its HBM streaming hides under MFMA compute;
// attn = R5-exact (best measured, 49.8us).

typedef __attribute__((ext_vector_type(8))) short short8;
typedef __attribute__((ext_vector_type(4))) float f32x4;

__device__ __forceinline__ ushort f2bf(float x) {
    union { __hip_bfloat16 h; ushort u; } v;
    v.h = __float2bfloat16(x);
    return v.u;
}
__device__ __forceinline__ float bf2f(ushort u) {
    union { uint u; float f; } v; v.u = ((uint)u) << 16; return v.f;
}
__device__ __forceinline__ uint cvtpk(float lo, float hi) {
    uint r;
    asm("v_cvt_pk_bf16_f32 %0, %1, %2" : "=v"(r) : "v"(lo), "v"(hi));
    return r;
}
__device__ __forceinline__ f32x4 mfma16(short8 a, short8 b, f32x4 c) {
    return __builtin_amdgcn_mfma_f32_16x16x32_bf16(a, b, c, 0, 0, 0);
}
// async global->LDS, 16B per lane. LDS dest = wave-uniform base + lane*16.
__device__ __forceinline__ void gl16(const void* g, const void* l) {
    __builtin_amdgcn_global_load_lds(
        (const __attribute__((address_space(1))) uint32_t*)(uintptr_t)g,
        (__attribute__((address_space(3))) uint32_t*)(uint32_t)(uintptr_t)l,
        16, 0, 0);
}

// ---------------------------------------------------------------------------
// prep: [0,12288)      convert query/key/value fp32 -> bf16 flat [8192][512]
//       [12288,13312)  convert Wq,Wk,Wv,Wh fp32 -> bf16 [512][512]
// ---------------------------------------------------------------------------
__global__ __launch_bounds__(256)
void prep(const float* __restrict__ q, const float* __restrict__ k,
          const float* __restrict__ v,
          const float* __restrict__ wq, const float* __restrict__ wk,
          const float* __restrict__ wv, const float* __restrict__ wh,
          ushort* __restrict__ qb, ushort* __restrict__ kb,
          ushort* __restrict__ vb,
          ushort* __restrict__ wqb, ushort* __restrict__ wkb,
          ushort* __restrict__ wvb, ushort* __restrict__ whb)
{
    const int bid = blockIdx.x, tid = threadIdx.x;
    if (bid < 12288) {
        size_t id = ((size_t)bid * 256 + tid) * 4;
        int t = (int)(id >> 22);
        size_t off = id & 4194303;
        const float* s = (t == 0) ? q : (t == 1) ? k : v;
        ushort* d = (t == 0) ? qb : (t == 1) ? kb : vb;
        float4 x = *(const float4*)(s + off);
        uint2 o; o.x = cvtpk(x.x, x.y); o.y = cvtpk(x.z, x.w);
        *(uint2*)(d + off) = o;
    } else {
        size_t id = ((size_t)(bid - 12288) * 256 + tid) * 4;
        int t = (int)(id >> 18);
        size_t off = id & 262143;
        const float* s = (t == 0) ? wq : (t == 1) ? wk : (t == 2) ? wv : wh;
        ushort* d = (t == 0) ? wqb : (t == 1) ? wkb : (t == 2) ? wvb : whb;
        float4 x = *(const float4*)(s + off);
        uint2 o; o.x = cvtpk(x.x, x.y); o.y = cvtpk(x.z, x.w);
        *(uint2*)(d + off) = o;
    }
}

// ---------------------------------------------------------------------------
// fused_g: blocks [0,768) = QKV GEMMs (z = bid>>8, mt = (bid&255)>>2,
// nt = bid&3); blocks [768,2816) = gm streaming (HBM-bound, hides under
// the MFMA blocks). GEMM path identical to the known-good gemm3.
// z=0: q_ws = (qb @ Wq^T) * 0.125*log2e (head layout); z=1: k_ws; z=2: vT.
// gm: gm[b][q][k] = (mask||q==k) ? bf16(gprob) : -1.0.
// ---------------------------------------------------------------------------
__global__ __launch_bounds__(256, 2)
void fused_g(const ushort* __restrict__ qb, const ushort* __restrict__ kb,
             const ushort* __restrict__ vb,
             const ushort* __restrict__ Wqb, const ushort* __restrict__ Wkb,
             const ushort* __restrict__ Wvb,
             const int* __restrict__ mask, const float* __restrict__ gp,
             ushort* __restrict__ q_ws, ushort* __restrict__ k_ws,
             ushort* __restrict__ vT, ushort* __restrict__ gmb)
{
    __shared__ __attribute__((aligned(16))) ushort As[8192];
    __shared__ __attribute__((aligned(16))) ushort Bs[8192];

    const int bid = blockIdx.x, tid = threadIdx.x;

    if (bid >= 768) {
        // ---- gm streaming: 2048 blocks x 256 thr x 4 sweeps x 4 elems ----
        const size_t base = ((size_t)(bid - 768) * 256 + tid) * 4;
        #pragma unroll
        for (int s = 0; s < 4; ++s) {
            size_t i = base + (size_t)s * 2097152;
            int4 m = *(const int4*)(mask + i);
            float4 gg = *(const float4*)(gp + i);
            int kk = (int)(i & 1023), qq = (int)((i >> 10) & 1023);
            uint u01 = cvtpk(gg.x, gg.y), u23 = cvtpk(gg.z, gg.w);
            ushort4 o;
            o.x = (m.x != 0 || qq == kk + 0) ? (ushort)(u01 & 0xffff) : (ushort)0xBF80;
            o.y = (m.y != 0 || qq == kk + 1) ? (ushort)(u01 >> 16)    : (ushort)0xBF80;
            o.z = (m.z != 0 || qq == kk + 2) ? (ushort)(u23 & 0xffff) : (ushort)0xBF80;
            o.w = (m.w != 0 || qq == kk + 3) ? (ushort)(u23 >> 16)    : (ushort)0xBF80;
            *(ushort4*)(gmb + i) = o;
        }
        return;
    }

    // ---- GEMM path (verbatim gemm3 logic) ----
    const int z = bid >> 8;
    const int tt2 = bid & 255;
    const int mt0 = tt2 >> 2, nt0 = tt2 & 3;
    const ushort* A = (z == 0) ? qb : (z == 1) ? kb : Wvb;
    const ushort* B = (z == 0) ? Wqb : (z == 1) ? Wkb : vb;
    const int mt = (z == 2) ? nt0 : mt0;
    const int nt = (z == 2) ? mt0 : nt0;
    const int m0 = mt * 128, n0 = nt * 128;
    const int lane = tid & 63, wave = tid >> 6;
    const int l15 = lane & 15, g = lane >> 4;
    const int wm = wave >> 1, wn = wave & 1;

    const int cb = (lane & 7) << 4;
    int soff[4];
    #pragma unroll
    for (int it = 0; it < 4; ++it) {
        int r = (it * 4 + wave) * 8 + (lane >> 3);
        soff[it] = r * 1024 + (cb ^ ((r & 7) << 4));
    }
    const char* Ab = (const char*)A + (size_t)m0 * 1024;
    const char* Bb = (const char*)B + (size_t)n0 * 1024;

    const int sw = (l15 & 7) << 4;
    const int c0 = (g * 16) ^ sw;
    const int c1 = (64 + g * 16) ^ sw;

    f32x4 acc[4][4];
    #pragma unroll
    for (int i = 0; i < 4; ++i)
        #pragma unroll
        for (int j = 0; j < 4; ++j) acc[i][j] = (f32x4){0.f, 0.f, 0.f, 0.f};

    for (int ks = 0; ks < 8; ++ks) {
        const int kof = ks * 128;
        #pragma unroll
        for (int it = 0; it < 4; ++it) {
            gl16(Ab + soff[it] + kof, (const char*)As + (it * 4 + wave) * 1024);
            gl16(Bb + soff[it] + kof, (const char*)Bs + (it * 4 + wave) * 1024);
        }
        __syncthreads();
        #pragma unroll
        for (int kk = 0; kk < 2; ++kk) {
            const int cc = kk ? c1 : c0;
            short8 af[4], bf[4];
            #pragma unroll
            for (int i = 0; i < 4; ++i)
                af[i] = *(const short8*)((const char*)As + (wm * 64 + i * 16 + l15) * 128 + cc);
            #pragma unroll
            for (int j = 0; j < 4; ++j)
                bf[j] = *(const short8*)((const char*)Bs + (wn * 64 + j * 16 + l15) * 128 + cc);
            #pragma unroll
            for (int i = 0; i < 4; ++i)
                #pragma unroll
                for (int j = 0; j < 4; ++j)
                    acc[i][j] = mfma16(af[i], bf[j], acc[i][j]);
        }
        __syncthreads();
    }

    #pragma unroll
    for (int i = 0; i < 4; ++i) {
        #pragma unroll
        for (int j = 0; j < 4; ++j) {
            #pragma unroll
            for (int r = 0; r < 4; ++r) {
                int mm = m0 + wm * 64 + i * 16 + g * 4 + r;
                int nn = n0 + wn * 64 + j * 16 + l15;
                float val = acc[i][j][r];
                if (z == 0) {
                    val *= 0.18033688f;   // 1/sqrt(64) * log2(e) folded into Q
                    int b = mm >> 10, s = mm & 1023, h = nn >> 6, dk = nn & 63;
                    q_ws[((((size_t)(b * 8 + h)) << 10) + s) * 64 + dk] = f2bf(val);
                } else if (z == 1) {
                    int b = mm >> 10, s = mm & 1023, h = nn >> 6, dk = nn & 63;
                    k_ws[((((size_t)(b * 8 + h)) << 10) + s) * 64 + dk] = f2bf(val);
                } else {
                    int h = mm >> 6, d = mm & 63, b = nn >> 10, s = nn & 1023;
                    vT[(((size_t)(b * 8 + h) * 64 + d) << 10) + s] = f2bf(val);
                }
            }
        }
    }
}

// ---------------------------------------------------------------------------
// Out projection (unchanged, known-good)
// ---------------------------------------------------------------------------
__global__ __launch_bounds__(256, 2)
void gemm_o(const ushort* __restrict__ Xh, const ushort* __restrict__ Whb,
            const float* __restrict__ bias, float* __restrict__ out)
{
    __shared__ __attribute__((aligned(16))) ushort As[8192];
    __shared__ __attribute__((aligned(16))) ushort Bs[8192];

    const int m0 = blockIdx.x * 128, n0 = blockIdx.y * 128;
    const int tid = threadIdx.x, lane = tid & 63, wave = tid >> 6;
    const int l15 = lane & 15, g = lane >> 4;
    const int wm = wave >> 1, wn = wave & 1;
    const int bb = m0 >> 10, s0 = m0 & 1023;

    const int cb = (lane & 7) << 4;
    int aoff[4], boff[4];
    #pragma unroll
    for (int it = 0; it < 4; ++it) {
        int r = (it * 4 + wave) * 8 + (lane >> 3);
        int swz = cb ^ ((r & 7) << 4);
        aoff[it] = ((bb * 8) * 1024 + s0 + r) * 128 + swz;  // +ks*131072
        boff[it] = (n0 + r) * 1024 + swz;                   // +ks*128
    }
    const int sw = (l15 & 7) << 4;
    const int c0 = (g * 16) ^ sw;
    const int c1 = (64 + g * 16) ^ sw;

    f32x4 acc[4][4];
    #pragma unroll
    for (int i = 0; i < 4; ++i)
        #pragma unroll
        for (int j = 0; j < 4; ++j) acc[i][j] = (f32x4){0.f, 0.f, 0.f, 0.f};

    for (int ks = 0; ks < 8; ++ks) {
        #pragma unroll
        for (int it = 0; it < 4; ++it) {
            gl16((const char*)Xh + aoff[it] + ks * 131072,
                 (const char*)As + (it * 4 + wave) * 1024);
            gl16((const char*)Whb + boff[it] + ks * 128,
                 (const char*)Bs + (it * 4 + wave) * 1024);
        }
        __syncthreads();
        #pragma unroll
        for (int kk = 0; kk < 2; ++kk) {
            const int cc = kk ? c1 : c0;
            short8 af[4], bf[4];
            #pragma unroll
            for (int i = 0; i < 4; ++i)
                af[i] = *(const short8*)((const char*)As + (wm * 64 + i * 16 + l15) * 128 + cc);
            #pragma unroll
            for (int j = 0; j < 4; ++j)
                bf[j] = *(const short8*)((const char*)Bs + (wn * 64 + j * 16 + l15) * 128 + cc);
            #pragma unroll
            for (int i = 0; i < 4; ++i)
                #pragma unroll
                for (int j = 0; j < 4; ++j)
                    acc[i][j] = mfma16(af[i], bf[j], acc[i][j]);
        }
        __syncthreads();
    }

    float bv[4];
    #pragma unroll
    for (int j = 0; j < 4; ++j) bv[j] = bias[n0 + wn * 64 + j * 16 + l15];

    #pragma unroll
    for (int i = 0; i < 4; ++i)
        #pragma unroll
        for (int j = 0; j < 4; ++j)
            #pragma unroll
            for (int r = 0; r < 4; ++r) {
                int mm = m0 + wm * 64 + i * 16 + g * 4 + r;
                int nn = n0 + wn * 64 + j * 16 + l15;
                out[(size_t)mm * 512 + nn] = acc[i][j][r] + bv[j];
            }
}

// ---------------------------------------------------------------------------
// attn: R5-exact (best measured, 49.8us). 4 waves x 32 q = 128 q / block,
// grid 512 (w = qt*64 + bh; XCD = bh%8). K/V staged via global_load_lds
// (sigma row-perm + XOR swizzle on per-lane SOURCE), double-buffered.
// No online max (Q pre-scaled to log2 domain; masked -> -1e9 -> exp2 = 0).
// ---------------------------------------------------------------------------
__global__ __launch_bounds__(256, 2)
void attn(const ushort* __restrict__ Qh, const ushort* __restrict__ Kh,
          const ushort* __restrict__ Vt, const ushort* __restrict__ gm,
          ushort* __restrict__ xo)
{
    __shared__ __attribute__((aligned(16))) ushort kv[2][2][4096];

    const int w = blockIdx.x;
    const int bh = w & 63, qt = w >> 6;
    const int tid = threadIdx.x, wave = tid >> 6, lane = tid & 63;
    const int l15 = lane & 15, g = lane >> 4;
    const int q0 = qt * 128 + wave * 32;      // this wave: q0..q0+31 (2 frags)
    const int b = bh >> 3;

    const char* Kpb = (const char*)(Kh + (size_t)bh * 65536);
    const char* Vpb = (const char*)(Vt + (size_t)bh * 65536);
    const ushort* QpA = Qh + ((size_t)bh * 1024 + q0 + l15) * 64;
    const ushort* QpB = QpA + 16 * 64;
    const ushort* gmpA = gm + ((size_t)b * 1024 + q0 + l15) * 1024;
    const ushort* gmpB = gmpA + 16 * 1024;

    const short8 qa0 = *(const short8*)(QpA + g * 8);
    const short8 qa1 = *(const short8*)(QpA + 32 + g * 8);
    const short8 qb0 = *(const short8*)(QpB + g * 8);
    const short8 qb1 = *(const short8*)(QpB + 32 + g * 8);

    // staging: LDS row p holds K global row gk(p) (sigma perm), V row p (id).
    const int cb = (lane & 7) << 4;
    const int rA = wave * 8 + (lane >> 3);
    const int rB = rA + 32;
    const int gkA = (rA & 3) + 4 * ((rA >> 4) & 1) + 8 * ((rA >> 2) & 3) + 32 * (rA >> 5);
    const int gkB = (rB & 3) + 4 * ((rB >> 4) & 1) + 8 * ((rB >> 2) & 3) + 32 * (rB >> 5);
    const int okA = gkA * 128 + (cb ^ ((rA & 7) << 4));
    const int okB = gkB * 128 + (cb ^ ((rB & 7) << 4));
    const int ovA = rA * 2048 + (cb ^ ((rA & 7) << 4));
    const int ovB = rB * 2048 + (cb ^ ((rB & 7) << 4));

    const int sw = (l15 & 7) << 4;
    const int c0 = (g * 16) ^ sw;
    const int c1 = (64 + g * 16) ^ sw;

    f32x4 otA[4], otB[4];
    #pragma unroll
    for (int t = 0; t < 4; ++t) {
        otA[t] = (f32x4){0.f, 0.f, 0.f, 0.f};
        otB[t] = (f32x4){0.f, 0.f, 0.f, 0.f};
    }
    float lsA = 0.f, lsB = 0.f;

    // prologue: tile 0 -> buf 0; gm tile 0 -> regs
    gl16(Kpb + okA, &kv[0][0][wave * 512]);
    gl16(Kpb + okB, &kv[0][0][(4 + wave) * 512]);
    gl16(Vpb + ovA, &kv[0][1][wave * 512]);
    gl16(Vpb + ovB, &kv[0][1][(4 + wave) * 512]);
    short8 gcA0 = *(const short8*)(gmpA + g * 8);
    short8 gcA1 = *(const short8*)(gmpA + 32 + g * 8);
    short8 gcB0 = *(const short8*)(gmpB + g * 8);
    short8 gcB1 = *(const short8*)(gmpB + 32 + g * 8);
    __syncthreads();

    for (int t = 0; t < 16; ++t) {
        const int cur = t & 1;
        short8 gnA0, gnA1, gnB0, gnB1;
        if (t < 15) {
            const char* kp = Kpb + (size_t)(t + 1) * 8192;
            const char* vp = Vpb + (size_t)(t + 1) * 128;
            gl16(kp + okA, &kv[cur ^ 1][0][wave * 512]);
            gl16(kp + okB, &kv[cur ^ 1][0][(4 + wave) * 512]);
            gl16(vp + ovA, &kv[cur ^ 1][1][wave * 512]);
            gl16(vp + ovB, &kv[cur ^ 1][1][(4 + wave) * 512]);
            gnA0 = *(const short8*)(gmpA + (t + 1) * 64 + g * 8);
            gnA1 = *(const short8*)(gmpA + (t + 1) * 64 + 32 + g * 8);
            gnB0 = *(const short8*)(gmpB + (t + 1) * 64 + g * 8);
            gnB1 = *(const short8*)(gmpB + (t + 1) * 64 + 32 + g * 8);
        }
        const char* kbuf = (const char*)&kv[cur][0][0];
        const char* vbuf = (const char*)&kv[cur][1][0];

        // QK^T (swapped) for both Q-frags; K-frag regs reused across frags.
        f32x4 sA[4], sB[4];
        #pragma unroll
        for (int t4 = 0; t4 < 4; ++t4) {
            const char* ka = kbuf + (t4 * 16 + l15) * 128;
            short8 k0f = *(const short8*)(ka + c0);
            short8 k1f = *(const short8*)(ka + c1);
            f32x4 za = (f32x4){0.f, 0.f, 0.f, 0.f};
            za = mfma16(k0f, qa0, za);
            za = mfma16(k1f, qa1, za);
            sA[t4] = za;
            f32x4 zb = (f32x4){0.f, 0.f, 0.f, 0.f};
            zb = mfma16(k0f, qb0, zb);
            zb = mfma16(k1f, qb1, zb);
            sB[t4] = zb;
        }

        // softmax (no max-tracking): p = exp2(s) (masked -> -1e9 -> 0)
        union { uint4 u; short8 s; } paA0, paA1, paB0, paB1;
        {
            float p[16], gv[16];
            #pragma unroll
            for (int c = 0; c < 2; ++c) {
                const short8 gc = c ? gcA1 : gcA0;
                #pragma unroll
                for (int j = 0; j < 8; ++j) {
                    const int jj = c * 8 + j;
                    const int t4 = 2 * c + (j >> 2), r = j & 3;
                    float gvv = bf2f((ushort)gc[j]);
                    gv[jj] = gvv;
                    p[jj] = exp2f((gvv >= 0.f) ? sA[t4][r] : -1.0e9f);
                }
            }
            lsA += (((p[0] + p[1]) + (p[2] + p[3])) + ((p[4] + p[5]) + (p[6] + p[7])))
                 + (((p[8] + p[9]) + (p[10] + p[11])) + ((p[12] + p[13]) + (p[14] + p[15])));
            paA0.u.x = cvtpk(p[0] * gv[0],  p[1] * gv[1]);
            paA0.u.y = cvtpk(p[2] * gv[2],  p[3] * gv[3]);
            paA0.u.z = cvtpk(p[4] * gv[4],  p[5] * gv[5]);
            paA0.u.w = cvtpk(p[6] * gv[6],  p[7] * gv[7]);
            paA1.u.x = cvtpk(p[8] * gv[8],  p[9] * gv[9]);
            paA1.u.y = cvtpk(p[10] * gv[10], p[11] * gv[11]);
            paA1.u.z = cvtpk(p[12] * gv[12], p[13] * gv[13]);
            paA1.u.w = cvtpk(p[14] * gv[14], p[15] * gv[15]);
        }
        {
            float p[16], gv[16];
            #pragma unroll
            for (int c = 0; c < 2; ++c) {
                const short8 gc = c ? gcB1 : gcB0;
                #pragma unroll
                for (int j = 0; j < 8; ++j) {
                    const int jj = c * 8 + j;
                    const int t4 = 2 * c + (j >> 2), r = j & 3;
                    float gvv = bf2f((ushort)gc[j]);
                    gv[jj] = gvv;
                    p[jj] = exp2f((gvv >= 0.f) ? sB[t4][r] : -1.0e9f);
                }
            }
            lsB += (((p[0] + p[1]) + (p[2] + p[3])) + ((p[4] + p[5]) + (p[6] + p[7])))
                 + (((p[8] + p[9]) + (p[10] + p[11])) + ((p[12] + p[13]) + (p[14] + p[15])));
            paB0.u.x = cvtpk(p[0] * gv[0],  p[1] * gv[1]);
            paB0.u.y = cvtpk(p[2] * gv[2],  p[3] * gv[3]);
            paB0.u.z = cvtpk(p[4] * gv[4],  p[5] * gv[5]);
            paB0.u.w = cvtpk(p[6] * gv[6],  p[7] * gv[7]);
            paB1.u.x = cvtpk(p[8] * gv[8],  p[9] * gv[9]);
            paB1.u.y = cvtpk(p[10] * gv[10], p[11] * gv[11]);
            paB1.u.z = cvtpk(p[12] * gv[12], p[13] * gv[13]);
            paB1.u.w = cvtpk(p[14] * gv[14], p[15] * gv[15]);
        }

        // PV for both frags; V-frag regs reused across frags.
        #pragma unroll
        for (int td = 0; td < 4; ++td) {
            const char* va = vbuf + (td * 16 + l15) * 128;
            short8 v0 = *(const short8*)(va + c0);
            short8 v1 = *(const short8*)(va + c1);
            otA[td] = mfma16(v0, paA0.s, otA[td]);
            otA[td] = mfma16(v1, paA1.s, otA[td]);
            otB[td] = mfma16(v0, paB0.s, otB[td]);
            otB[td] = mfma16(v1, paB1.s, otB[td]);
        }
        __syncthreads();
        if (t < 15) { gcA0 = gnA0; gcA1 = gnA1; gcB0 = gnB0; gcB1 = gnB1; }
    }

    lsA += __shfl_xor(lsA, 16, 64);
    lsA += __shfl_xor(lsA, 32, 64);
    lsB += __shfl_xor(lsB, 16, 64);
    lsB += __shfl_xor(lsB, 32, 64);
    const float invA = 1.0f / lsA;
    const float invB = 1.0f / lsB;

    ushort* xpA = xo + ((size_t)bh * 1024 + q0 + l15) * 64;
    ushort* xpB = xpA + 16 * 64;
    #pragma unroll
    for (int td = 0; td < 4; ++td) {
        uint2 oa, ob;
        oa.x = cvtpk(otA[td][0] * invA, otA[td][1] * invA);
        oa.y = cvtpk(otA[td][2] * invA, otA[td][3] * invA);
        ob.x = cvtpk(otB[td][0] * invB, otB[td][1] * invB);
        ob.y = cvtpk(otB[td][2] * invB, otB[td][3] * invB);
        *(uint2*)(xpA + td * 16 + g * 4) = oa;
        *(uint2*)(xpB + td * 16 + g * 4) = ob;
    }
}

// ---------------------------------------------------------------------------
extern "C" void kernel_launch(void* const* d_in, const int* in_sizes, int n_in,
                              void* d_out, int out_size, void* d_ws, size_t ws_size,
                              hipStream_t stream)
{
    const float* query = (const float*)d_in[0];
    const float* key   = (const float*)d_in[1];
    const float* value = (const float*)d_in[2];
    const float* gprob = (const float*)d_in[3];
    const float* Wq    = (const float*)d_in[4];
    const float* Wk    = (const float*)d_in[5];
    const float* Wv    = (const float*)d_in[6];
    const float* Wh    = (const float*)d_in[7];
    const float* bh    = (const float*)d_in[8];
    const int*   mask  = (const int*)d_in[9];
    float* out = (float*)d_out;

    ushort* ws = (ushort*)d_ws;
    const size_t HS = (size_t)64 * 65536;   // 4,194,304
    ushort* q_ws = ws;
    ushort* k_ws = ws + HS;
    ushort* vT   = ws + 2 * HS;
    ushort* gmb  = ws + 3 * HS;             // 2*HS elems
    ushort* qb   = ws + 5 * HS;
    ushort* kb   = ws + 6 * HS;
    ushort* vb   = ws + 7 * HS;
    ushort* wqb  = ws + 8 * HS;
    ushort* wkb  = wqb + 262144;
    ushort* wvb  = wkb + 262144;
    ushort* whb  = wvb + 262144;
    ushort* x_ws = qb;                      // alias: qb dead after fused_g

    prep<<<13312, 256, 0, stream>>>(query, key, value, Wq, Wk, Wv, Wh,
                                    qb, kb, vb, wqb, wkb, wvb, whb);
    fused_g<<<2816, 256, 0, stream>>>(qb, kb, vb, wqb, wkb, wvb,
                                      mask, gprob, q_ws, k_ws, vT, gmb);
    attn<<<512, 256, 0, stream>>>(q_ws, k_ws, vT, gmb, x_ws);
    gemm_o<<<dim3(64, 4), 256, 0, stream>>>(x_ws, whb, bh, out);
}